// Round 16
// baseline (173.945 us; speedup 1.0000x reference)
//
#include <hip/hip_runtime.h>
#include <hip/hip_fp16.h>
#include <cstdint>
#include <cstddef>

#define NN 50000
#define EE 800000
#define ETOT (EE + NN)   // edges + self loops
#define FD 128
#define NH 4
#define NEG_SLOPE 0.2f

#define BSHIFT 10
#define BSIZE 1024
#define NBKT ((NN + BSIZE - 1) / BSIZE)      // 49
#define CAPG 20000
#define CHUNK 2048
#define P1_BLOCKS ((ETOT + CHUNK - 1) / CHUNK)          // 416
#define GEMM_BLOCKS ((NN + 63) / 64)                    // 782
#define ADOTX_BLOCKS ((NN * 16 + 255) / 256)            // 3125

typedef _Float16 half8 __attribute__((ext_vector_type(8)));
typedef float f32x4 __attribute__((ext_vector_type(4)));

// ---------------- shared device bodies ----------------

__device__ __forceinline__ void gemm_body(const float* __restrict__ X,
                                          const uint4* __restrict__ Wf,
                                          __half* __restrict__ Hh,
                                          int bidx, int tid) {
    const int wv = tid >> 6, lane = tid & 63;
    const int l15 = lane & 15, lg = lane >> 4;
    const int rowA = bidx * 64 + wv * 16 + l15;
    const int rA = (rowA < NN) ? rowA : NN - 1;      // clamp loads; stores guarded
    half8 a[4];
    #pragma unroll
    for (int ks = 0; ks < 4; ++ks) {
        int kb = ks * 32 + lg * 8;
        float4 x0 = *(const float4*)&X[(size_t)rA * FD + kb];
        float4 x1 = *(const float4*)&X[(size_t)rA * FD + kb + 4];
        a[ks][0] = (_Float16)x0.x; a[ks][1] = (_Float16)x0.y;
        a[ks][2] = (_Float16)x0.z; a[ks][3] = (_Float16)x0.w;
        a[ks][4] = (_Float16)x1.x; a[ks][5] = (_Float16)x1.y;
        a[ks][6] = (_Float16)x1.z; a[ks][7] = (_Float16)x1.w;
    }
    const int rowC = bidx * 64 + wv * 16 + lg * 4;
    #pragma unroll
    for (int ct = 0; ct < 8; ++ct) {
        uint4 braw[4];
        #pragma unroll
        for (int ks = 0; ks < 4; ++ks) braw[ks] = Wf[(ct * 4 + ks) * 64 + lane];
        f32x4 acc = {0.f, 0.f, 0.f, 0.f};
        #pragma unroll
        for (int ks = 0; ks < 4; ++ks) {
            half8 b = *(half8*)&braw[ks];
            acc = __builtin_amdgcn_mfma_f32_16x16x32_f16(a[ks], b, acc, 0, 0, 0);
        }
        #pragma unroll
        for (int r = 0; r < 4; ++r) {
            int gr = rowC + r;
            if (gr < NN) Hh[(size_t)gr * FD + ct * 16 + l15] = __float2half(acc[r]);
        }
    }
}

// attention half-dots from the fp32 pre-GEMM activations:
// AS[n][h] = sum_k X[n,k] * WA[k][h], WA precomputed (128 x 8, o<4: src, o>=4: dst)
__device__ __forceinline__ void adotx_body(const float* __restrict__ X,
                                           const float* __restrict__ WA,
                                           float* __restrict__ AS,
                                           float* __restrict__ AD, int gt) {
    int n = gt >> 4;
    int l = gt & 15;                      // lane owns k in [l*8, l*8+8)
    if (n >= NN) return;
    float4 v0 = *(const float4*)&X[(size_t)n * FD + l * 8];
    float4 v1 = *(const float4*)&X[(size_t)n * FD + l * 8 + 4];
    float xv[8] = {v0.x, v0.y, v0.z, v0.w, v1.x, v1.y, v1.z, v1.w};
    float p[8] = {};
    #pragma unroll
    for (int j = 0; j < 8; ++j) {
        const float4 w0 = *(const float4*)&WA[(l * 8 + j) * 8];
        const float4 w1 = *(const float4*)&WA[(l * 8 + j) * 8 + 4];
        p[0] += xv[j] * w0.x; p[1] += xv[j] * w0.y;
        p[2] += xv[j] * w0.z; p[3] += xv[j] * w0.w;
        p[4] += xv[j] * w1.x; p[5] += xv[j] * w1.y;
        p[6] += xv[j] * w1.z; p[7] += xv[j] * w1.w;
    }
    #pragma unroll
    for (int m = 1; m <= 8; m <<= 1)
        #pragma unroll
        for (int o = 0; o < 8; ++o) p[o] += __shfl_xor(p[o], m);
    if (l == 0) {
        *(float4*)&AS[n * NH] = make_float4(p[0], p[1], p[2], p[3]);
        *(float4*)&AD[n * NH] = make_float4(p[4], p[5], p[6], p[7]);
    }
}

// ---------------- D1: zero gcnt || Wf prep || WA prep ----------------

__global__ __launch_bounds__(256) void init_kernel(int* __restrict__ gcnt,
                                                   const float* __restrict__ W1,
                                                   const float* __restrict__ W2,
                                                   uint4* __restrict__ Wf1,
                                                   uint4* __restrict__ Wf2,
                                                   const float* __restrict__ asrc1,
                                                   const float* __restrict__ adst1,
                                                   const float* __restrict__ asrc2,
                                                   const float* __restrict__ adst2,
                                                   float* __restrict__ WA1,
                                                   float* __restrict__ WA2) {
    if (blockIdx.x == 0) {
        if (threadIdx.x < NBKT) gcnt[threadIdx.x] = 0;
        return;
    }
    if (blockIdx.x <= 2) {                 // Wf prep
        const float* W = (blockIdx.x == 2) ? W2 : W1;
        uint4* Wf = (blockIdx.x == 2) ? Wf2 : Wf1;
        for (int s = threadIdx.x; s < 2048; s += 256) {
            int fi = s >> 6;
            int lane = s & 63;
            int ct = fi >> 2, ks = fi & 3;
            int col = ct * 16 + (lane & 15);
            int kb = ks * 32 + (lane >> 4) * 8;
            half8 h;
            #pragma unroll
            for (int j = 0; j < 8; ++j) h[j] = (_Float16)W[(kb + j) * FD + col];
            Wf[s] = *(uint4*)&h;
        }
        return;
    }
    // WA prep: WA[k*8+o] = sum_j W[k, (o&3)*32+j] * a[(o&3)*32+j]
    const float* W  = (blockIdx.x == 4) ? W2 : W1;
    const float* as = (blockIdx.x == 4) ? asrc2 : asrc1;
    const float* ad = (blockIdx.x == 4) ? adst2 : adst1;
    float* WA = (blockIdx.x == 4) ? WA2 : WA1;
    for (int idx = threadIdx.x; idx < 1024; idx += 256) {
        int k = idx >> 3, o = idx & 7;
        int h = o & 3;
        const float* a = (o < 4) ? as : ad;
        float s = 0.f;
        #pragma unroll 8
        for (int j = 0; j < 32; ++j)
            s += W[k * FD + h * 32 + j] * a[h * 32 + j];
        WA[k * 8 + o] = s;
    }
}

// ---------------- D2: bin || gemm L1 || adotx L1 ----------------

__global__ __launch_bounds__(256) void binGemm_kernel(const int* __restrict__ ei,
                                                      int* __restrict__ gcnt,
                                                      uint32_t* __restrict__ gbkt,
                                                      const float* __restrict__ X,
                                                      const uint4* __restrict__ Wf1,
                                                      __half* __restrict__ Hh,
                                                      const float* __restrict__ WA1,
                                                      float* __restrict__ AS,
                                                      float* __restrict__ AD) {
    if (blockIdx.x >= P1_BLOCKS + GEMM_BLOCKS) {
        adotx_body(X, WA1, AS, AD,
                   (blockIdx.x - P1_BLOCKS - GEMM_BLOCKS) * 256 + threadIdx.x);
        return;
    }
    if (blockIdx.x >= P1_BLOCKS) {
        gemm_body(X, Wf1, Hh, blockIdx.x - P1_BLOCKS, threadIdx.x);
        return;
    }
    __shared__ int lcnt[NBKT];
    __shared__ int gb[NBKT];
    const int t = threadIdx.x;
    if (t < NBKT) lcnt[t] = 0;
    __syncthreads();
    const int base = blockIdx.x * CHUNK;
    uint32_t pk[8]; int bk[8]; int sl[8];
    #pragma unroll
    for (int j = 0; j < 8; ++j) {
        int e = base + j * 256 + t;
        bk[j] = -1;
        if (e < ETOT) {
            int src, dst;
            if (e < EE) { src = ei[e]; dst = ei[EE + e]; }
            else        { src = e - EE; dst = src; }
            int b = dst >> BSHIFT;
            bk[j] = b;
            pk[j] = (uint32_t)src | ((uint32_t)(dst & (BSIZE - 1)) << 16);
            sl[j] = atomicAdd(&lcnt[b], 1);
        }
    }
    __syncthreads();
    if (t < NBKT) gb[t] = atomicAdd(&gcnt[t], lcnt[t]);
    __syncthreads();
    #pragma unroll
    for (int j = 0; j < 8; ++j)
        if (bk[j] >= 0)
            gbkt[(size_t)bk[j] * CAPG + gb[bk[j]] + sl[j]] = pk[j];
}

// ---------------- D3: per-bucket counting sort ----------------

__global__ __launch_bounds__(1024) void sort_kernel(const int* __restrict__ gcnt,
                                                    const uint32_t* __restrict__ gbkt,
                                                    int* __restrict__ row_ptr,
                                                    int* __restrict__ csr) {
    __shared__ int cnt[BSIZE];
    __shared__ int pfx[BSIZE];
    __shared__ int wsum[16];
    __shared__ int sCbase;
    const int b = blockIdx.x;
    const int t = threadIdx.x;
    const int count = gcnt[b];
    const int dstBase = b << BSHIFT;
    const int ndst = (NN - dstBase < BSIZE) ? (NN - dstBase) : BSIZE;
    const uint32_t* mybkt = gbkt + (size_t)b * CAPG;
    cnt[t] = 0;
    if (t < 64) {                       // wave 0: exclusive scan of 49 bucket counts
        int v = (t < NBKT) ? gcnt[t] : 0;
        int inc = v;
        #pragma unroll
        for (int off = 1; off < 64; off <<= 1) {
            int u = __shfl_up(inc, off);
            if (t >= off) inc += u;
        }
        if (t == b) sCbase = inc - v;
    }
    __syncthreads();
    const int cbase = sCbase;
    for (int i = t; i < count; i += 1024)
        atomicAdd(&cnt[mybkt[i] >> 16], 1);
    __syncthreads();
    int v = cnt[t];
    int inc = v;
    const int lane = t & 63, wid = t >> 6;
    #pragma unroll
    for (int off = 1; off < 64; off <<= 1) {
        int u = __shfl_up(inc, off);
        if (lane >= off) inc += u;
    }
    if (lane == 63) wsum[wid] = inc;
    __syncthreads();
    if (t < 16) {
        int w = wsum[t]; int wi = w;
        #pragma unroll
        for (int off = 1; off < 16; off <<= 1) {
            int u = __shfl_up(wi, off);
            if (t >= off) wi += u;
        }
        wsum[t] = wi - w;
    }
    __syncthreads();
    int excl = wsum[wid] + inc - v;
    pfx[t] = excl;
    if (t < ndst) row_ptr[dstBase + t] = cbase + excl;
    if (b == NBKT - 1 && t == 0) row_ptr[NN] = ETOT;
    cnt[t] = 0;
    __syncthreads();
    for (int i = t; i < count; i += 1024) {
        uint32_t pkv = mybkt[i];
        int dl = pkv >> 16;
        int r = atomicAdd(&cnt[dl], 1);
        csr[cbase + pfx[dl] + r] = (int)(pkv & 0xFFFFu);
    }
}

// ---------------- D5: gemm L2 || adotx L2 (both read `out`, disjoint writes) ----------------

__global__ __launch_bounds__(256) void gemmAdot_kernel(const float* __restrict__ X,
                                                       const uint4* __restrict__ Wf,
                                                       __half* __restrict__ Hh,
                                                       const float* __restrict__ WA,
                                                       float* __restrict__ AS,
                                                       float* __restrict__ AD) {
    if (blockIdx.x >= GEMM_BLOCKS) {
        adotx_body(X, WA, AS, AD, (blockIdx.x - GEMM_BLOCKS) * 256 + threadIdx.x);
        return;
    }
    gemm_body(X, Wf, Hh, blockIdx.x, threadIdx.x);
}

// ---------------- aggregation: TWO nodes per wave; softmax sum folded into gather ----------------

__global__ __launch_bounds__(256) void agg_kernel(const __half* __restrict__ H,
                                                  const float* __restrict__ AS,
                                                  const float* __restrict__ AD,
                                                  const int* __restrict__ row_ptr,
                                                  const int* __restrict__ csr_src,
                                                  const float* __restrict__ bias,
                                                  float* __restrict__ Out) {
    __shared__ float sP[8][32][4];   // [waveslot][edge][head], one ds_write_b128/lane
    __shared__ int   sS[8][32];
    const int wave = threadIdx.x >> 6;
    const int lane = threadIdx.x & 63;
    const int sub  = lane >> 5;
    const int sl   = lane & 31;
    const int ws   = wave * 2 + sub;
    const int n = blockIdx.x * 8 + ws;            // grid = NN/8 exactly
    const int start = row_ptr[n], end = row_ptr[n + 1];
    const int h0 = sl >> 3;                       // head of this lane's 4 channels
    const float4 adv = *(const float4*)&AD[n * NH];
    float spm = 0.f;                              // running sum of pm for head h0
    float acc0 = 0.f, acc1 = 0.f, acc2 = 0.f, acc3 = 0.f;

    for (int base = start; base < end; base += 32) {
        int cn = end - base; if (cn > 32) cn = 32;
        int my_src = 0;
        float al[NH] = {0.f, 0.f, 0.f, 0.f};
        if (sl < cn) {
            my_src = csr_src[base + sl];
            float4 asv = *(const float4*)&AS[my_src * NH];
            al[0] = asv.x + adv.x; al[1] = asv.y + adv.y;
            al[2] = asv.z + adv.z; al[3] = asv.w + adv.w;
        }
        sS[ws][sl] = my_src;
        float4 pv;
        {
            float a0 = (al[0] > 0.f) ? al[0] : NEG_SLOPE * al[0];
            float a1 = (al[1] > 0.f) ? al[1] : NEG_SLOPE * al[1];
            float a2 = (al[2] > 0.f) ? al[2] : NEG_SLOPE * al[2];
            float a3 = (al[3] > 0.f) ? al[3] : NEG_SLOPE * al[3];
            pv.x = __expf(a0); pv.y = __expf(a1);
            pv.z = __expf(a2); pv.w = __expf(a3);
        }
        *(float4*)&sP[ws][sl][0] = pv;            // entries e>=cn never read
        #pragma unroll 4
        for (int e = 0; e < cn; ++e) {
            float pm = sP[ws][e][h0];
            int se = sS[ws][e];
            union { uint2 u; __half2 q[2]; } hv;
            hv.u = *(const uint2*)&H[(size_t)se * FD + sl * 4];
            float2 f0 = __half22float2(hv.q[0]);
            float2 f1 = __half22float2(hv.q[1]);
            acc0 += pm * f0.x; acc1 += pm * f0.y;
            acc2 += pm * f1.x; acc3 += pm * f1.y;
            spm  += pm;
        }
    }
    float inv = 1.f / (spm + 1e-16f);
    const float4 bv = *(const float4*)&bias[sl * 4];
    float4 ov;
    ov.x = fmaxf(acc0 * inv + bv.x, 0.f);
    ov.y = fmaxf(acc1 * inv + bv.y, 0.f);
    ov.z = fmaxf(acc2 * inv + bv.z, 0.f);
    ov.w = fmaxf(acc3 * inv + bv.w, 0.f);
    *(float4*)&Out[(size_t)n * FD + sl * 4] = ov;
}

// ---------------- launch (6 dispatches) ----------------

extern "C" void kernel_launch(void* const* d_in, const int* in_sizes, int n_in,
                              void* d_out, int out_size, void* d_ws, size_t ws_size,
                              hipStream_t stream) {
    const float* x     = (const float*)d_in[0];
    const int*   ei    = (const int*)d_in[1];
    const float* W1    = (const float*)d_in[2];
    const float* asrc1 = (const float*)d_in[3];
    const float* adst1 = (const float*)d_in[4];
    const float* b1    = (const float*)d_in[5];
    const float* W2    = (const float*)d_in[6];
    const float* asrc2 = (const float*)d_in[7];
    const float* adst2 = (const float*)d_in[8];
    const float* b2    = (const float*)d_in[9];
    float* out = (float*)d_out;

    char* p = (char*)d_ws;
    auto alloc = [&](size_t bytes) {
        char* q = p;
        p += (bytes + 255) & ~(size_t)255;
        return q;
    };
    int*      row_ptr = (int*)alloc((NN + 1) * sizeof(int));
    int*      gcnt    = (int*)alloc(NBKT * sizeof(int));
    uint32_t* gbkt    = (uint32_t*)alloc((size_t)NBKT * CAPG * sizeof(uint32_t));
    int*      csr     = (int*)alloc((size_t)ETOT * sizeof(int));
    float*    AS      = (float*)alloc((size_t)NN * NH * sizeof(float));
    float*    AD      = (float*)alloc((size_t)NN * NH * sizeof(float));
    __half*   Hh      = (__half*)alloc((size_t)NN * FD * sizeof(__half));
    uint4*    Wf1     = (uint4*)alloc(2048 * sizeof(uint4));
    uint4*    Wf2     = (uint4*)alloc(2048 * sizeof(uint4));
    float*    WA1     = (float*)alloc(1024 * sizeof(float));
    float*    WA2     = (float*)alloc(1024 * sizeof(float));
    (void)ws_size; (void)in_sizes; (void)n_in; (void)out_size;

    // D1: zero gcnt || Wf prep || WA prep
    init_kernel<<<5, 256, 0, stream>>>(gcnt, W1, W2, Wf1, Wf2,
                                       asrc1, adst1, asrc2, adst2, WA1, WA2);
    // D2: bin edges || gemm L1 || adotx L1
    binGemm_kernel<<<P1_BLOCKS + GEMM_BLOCKS + ADOTX_BLOCKS, 256, 0, stream>>>(
        ei, gcnt, gbkt, x, Wf1, Hh, WA1, AS, AD);
    // D3: bucket sort
    sort_kernel<<<NBKT, 1024, 0, stream>>>(gcnt, gbkt, row_ptr, csr);
    // D4: agg layer 1
    agg_kernel<<<NN / 8, 256, 0, stream>>>(Hh, AS, AD, row_ptr, csr, b1, out);
    // D5: gemm L2 || adotx L2
    gemmAdot_kernel<<<GEMM_BLOCKS + ADOTX_BLOCKS, 256, 0, stream>>>(
        out, Wf2, Hh, WA2, AS, AD);
    // D6: agg layer 2
    agg_kernel<<<NN / 8, 256, 0, stream>>>(Hh, AS, AD, row_ptr, csr, b2, out);
}

// Round 17
// 133.121 us; speedup vs baseline: 1.3067x; 1.3067x over previous
//
#include <hip/hip_runtime.h>
#include <hip/hip_fp16.h>
#include <cstdint>
#include <cstddef>

#define NN 50000
#define EE 800000
#define ETOT (EE + NN)   // edges + self loops
#define FD 128
#define NH 4
#define NEG_SLOPE 0.2f

#define BSHIFT 10
#define BSIZE 1024
#define NBKT ((NN + BSIZE - 1) / BSIZE)      // 49
#define CAPG 20000
#define CHUNK 2048
#define P1_BLOCKS ((ETOT + CHUNK - 1) / CHUNK)          // 416
#define GEMM_BLOCKS ((NN + 63) / 64)                    // 782
#define ADOT_BLOCKS ((NN * 16 + 1023) / 1024)           // 782

typedef _Float16 half8 __attribute__((ext_vector_type(8)));
typedef _Float16 half2v __attribute__((ext_vector_type(2)));
typedef float f32x4 __attribute__((ext_vector_type(4)));

// ---------------- shared device bodies ----------------

__device__ __forceinline__ void gemm_body(const float* __restrict__ X,
                                          const uint4* __restrict__ Wf,
                                          __half* __restrict__ Hh,
                                          int bidx, int tid) {
    const int wv = tid >> 6, lane = tid & 63;
    const int l15 = lane & 15, lg = lane >> 4;
    const int rowA = bidx * 64 + wv * 16 + l15;
    const int rA = (rowA < NN) ? rowA : NN - 1;      // clamp loads; stores guarded
    half8 a[4];
    #pragma unroll
    for (int ks = 0; ks < 4; ++ks) {
        int kb = ks * 32 + lg * 8;
        float4 x0 = *(const float4*)&X[(size_t)rA * FD + kb];
        float4 x1 = *(const float4*)&X[(size_t)rA * FD + kb + 4];
        a[ks][0] = (_Float16)x0.x; a[ks][1] = (_Float16)x0.y;
        a[ks][2] = (_Float16)x0.z; a[ks][3] = (_Float16)x0.w;
        a[ks][4] = (_Float16)x1.x; a[ks][5] = (_Float16)x1.y;
        a[ks][6] = (_Float16)x1.z; a[ks][7] = (_Float16)x1.w;
    }
    const int rowC = bidx * 64 + wv * 16 + lg * 4;
    #pragma unroll
    for (int ct = 0; ct < 8; ++ct) {
        uint4 braw[4];
        #pragma unroll
        for (int ks = 0; ks < 4; ++ks) braw[ks] = Wf[(ct * 4 + ks) * 64 + lane];
        f32x4 acc = {0.f, 0.f, 0.f, 0.f};
        #pragma unroll
        for (int ks = 0; ks < 4; ++ks) {
            half8 b = *(half8*)&braw[ks];
            acc = __builtin_amdgcn_mfma_f32_16x16x32_f16(a[ks], b, acc, 0, 0, 0);
        }
        #pragma unroll
        for (int r = 0; r < 4; ++r) {
            int gr = rowC + r;
            if (gr < NN) Hh[(size_t)gr * FD + ct * 16 + l15] = __float2half(acc[r]);
        }
    }
}

__device__ __forceinline__ void adot_body(const __half* __restrict__ H,
                                          const float* __restrict__ a_src,
                                          const float* __restrict__ a_dst,
                                          float* __restrict__ AS,
                                          float* __restrict__ AD, int gt) {
    int n = gt >> 4;
    int l = gt & 15;
    if (n >= NN) return;
    union { uint4 u; __half2 q[4]; } hv;
    hv.u = *(const uint4*)&H[(size_t)n * FD + l * 8];
    float ps = 0.f, pd = 0.f;
    #pragma unroll
    for (int j = 0; j < 4; ++j) {
        float2 f = __half22float2(hv.q[j]);
        ps += f.x * a_src[l * 8 + 2 * j] + f.y * a_src[l * 8 + 2 * j + 1];
        pd += f.x * a_dst[l * 8 + 2 * j] + f.y * a_dst[l * 8 + 2 * j + 1];
    }
    ps += __shfl_xor(ps, 1); ps += __shfl_xor(ps, 2);
    pd += __shfl_xor(pd, 1); pd += __shfl_xor(pd, 2);
    if ((l & 3) == 0) {
        AS[n * NH + (l >> 2)] = ps;
        AD[n * NH + (l >> 2)] = pd;
    }
}

// ---------------- D1: zero gcnt  ||  W -> MFMA fragment order ----------------

__global__ __launch_bounds__(256) void init_kernel(int* __restrict__ gcnt,
                                                   const float* __restrict__ W1,
                                                   const float* __restrict__ W2,
                                                   uint4* __restrict__ Wf1,
                                                   uint4* __restrict__ Wf2) {
    if (blockIdx.x == 0) {
        if (threadIdx.x < NBKT) gcnt[threadIdx.x] = 0;
        return;
    }
    const float* W = (blockIdx.x == 2) ? W2 : W1;
    uint4* Wf = (blockIdx.x == 2) ? Wf2 : Wf1;
    for (int s = threadIdx.x; s < 2048; s += 256) {
        int fi = s >> 6;
        int lane = s & 63;
        int ct = fi >> 2, ks = fi & 3;
        int col = ct * 16 + (lane & 15);
        int kb = ks * 32 + (lane >> 4) * 8;
        half8 h;
        #pragma unroll
        for (int j = 0; j < 8; ++j) h[j] = (_Float16)W[(kb + j) * FD + col];
        Wf[s] = *(uint4*)&h;
    }
}

// ---------------- D2: bin (blocks [0,416))  ||  gemm layer 1 (blocks [416,1198)) ----------------

__global__ __launch_bounds__(256) void binGemm_kernel(const int* __restrict__ ei,
                                                      int* __restrict__ gcnt,
                                                      uint32_t* __restrict__ gbkt,
                                                      const float* __restrict__ X,
                                                      const uint4* __restrict__ Wf1,
                                                      __half* __restrict__ Hh) {
    if (blockIdx.x >= P1_BLOCKS) {
        gemm_body(X, Wf1, Hh, blockIdx.x - P1_BLOCKS, threadIdx.x);
        return;
    }
    __shared__ int lcnt[NBKT];
    __shared__ int gb[NBKT];
    const int t = threadIdx.x;
    if (t < NBKT) lcnt[t] = 0;
    __syncthreads();
    const int base = blockIdx.x * CHUNK;
    uint32_t pk[8]; int bk[8]; int sl[8];
    #pragma unroll
    for (int j = 0; j < 8; ++j) {
        int e = base + j * 256 + t;
        bk[j] = -1;
        if (e < ETOT) {
            int src, dst;
            if (e < EE) { src = ei[e]; dst = ei[EE + e]; }
            else        { src = e - EE; dst = src; }
            int b = dst >> BSHIFT;
            bk[j] = b;
            pk[j] = (uint32_t)src | ((uint32_t)(dst & (BSIZE - 1)) << 16);
            sl[j] = atomicAdd(&lcnt[b], 1);
        }
    }
    __syncthreads();
    if (t < NBKT) gb[t] = atomicAdd(&gcnt[t], lcnt[t]);
    __syncthreads();
    #pragma unroll
    for (int j = 0; j < 8; ++j)
        if (bk[j] >= 0)
            gbkt[(size_t)bk[j] * CAPG + gb[bk[j]] + sl[j]] = pk[j];
}

// ---------------- D3: sort (blocks [0,49))  ||  adot layer 1 (blocks [49,831)) ----------------

__global__ __launch_bounds__(1024) void sortAdot_kernel(const int* __restrict__ gcnt,
                                                        const uint32_t* __restrict__ gbkt,
                                                        int* __restrict__ row_ptr,
                                                        int* __restrict__ csr,
                                                        const __half* __restrict__ Hh,
                                                        const float* __restrict__ a_src,
                                                        const float* __restrict__ a_dst,
                                                        float* __restrict__ AS,
                                                        float* __restrict__ AD) {
    if (blockIdx.x >= NBKT) {
        adot_body(Hh, a_src, a_dst, AS, AD,
                  (blockIdx.x - NBKT) * 1024 + threadIdx.x);
        return;
    }
    __shared__ int cnt[BSIZE];
    __shared__ int pfx[BSIZE];
    __shared__ int wsum[16];
    __shared__ int sCbase;
    const int b = blockIdx.x;
    const int t = threadIdx.x;
    const int count = gcnt[b];
    const int dstBase = b << BSHIFT;
    const int ndst = (NN - dstBase < BSIZE) ? (NN - dstBase) : BSIZE;
    const uint32_t* mybkt = gbkt + (size_t)b * CAPG;
    cnt[t] = 0;
    if (t < 64) {                       // wave 0: exclusive scan of 49 bucket counts
        int v = (t < NBKT) ? gcnt[t] : 0;
        int inc = v;
        #pragma unroll
        for (int off = 1; off < 64; off <<= 1) {
            int u = __shfl_up(inc, off);
            if (t >= off) inc += u;
        }
        if (t == b) sCbase = inc - v;
    }
    __syncthreads();
    const int cbase = sCbase;
    for (int i = t; i < count; i += 1024)
        atomicAdd(&cnt[mybkt[i] >> 16], 1);
    __syncthreads();
    int v = cnt[t];
    int inc = v;
    const int lane = t & 63, wid = t >> 6;
    #pragma unroll
    for (int off = 1; off < 64; off <<= 1) {
        int u = __shfl_up(inc, off);
        if (lane >= off) inc += u;
    }
    if (lane == 63) wsum[wid] = inc;
    __syncthreads();
    if (t < 16) {
        int w = wsum[t]; int wi = w;
        #pragma unroll
        for (int off = 1; off < 16; off <<= 1) {
            int u = __shfl_up(wi, off);
            if (t >= off) wi += u;
        }
        wsum[t] = wi - w;
    }
    __syncthreads();
    int excl = wsum[wid] + inc - v;
    pfx[t] = excl;
    if (t < ndst) row_ptr[dstBase + t] = cbase + excl;
    if (b == NBKT - 1 && t == 0) row_ptr[NN] = ETOT;
    cnt[t] = 0;
    __syncthreads();
    for (int i = t; i < count; i += 1024) {
        uint32_t pkv = mybkt[i];
        int dl = pkv >> 16;
        int r = atomicAdd(&cnt[dl], 1);
        csr[cbase + pfx[dl] + r] = (int)(pkv & 0xFFFFu);
    }
}

// ---------------- standalone gemm / adot for layer 2 ----------------

__global__ __launch_bounds__(256) void gemm_kernel(const float* __restrict__ X,
                                                   const uint4* __restrict__ Wf,
                                                   __half* __restrict__ Hh) {
    gemm_body(X, Wf, Hh, blockIdx.x, threadIdx.x);
}

__global__ __launch_bounds__(256) void adot_kernel(const __half* __restrict__ H,
                                                   const float* __restrict__ a_src,
                                                   const float* __restrict__ a_dst,
                                                   float* __restrict__ AS,
                                                   float* __restrict__ AD) {
    adot_body(H, a_src, a_dst, AS, AD, blockIdx.x * 256 + threadIdx.x);
}

// ---------------- aggregation: TWO nodes per wave; softmax sum folded into gather ----------------
// Inner loop uses (float)h16 * pm + acc  ->  v_fma_mix_f32 (no separate cvt).

__global__ __launch_bounds__(256) void agg_kernel(const __half* __restrict__ H,
                                                  const float* __restrict__ AS,
                                                  const float* __restrict__ AD,
                                                  const int* __restrict__ row_ptr,
                                                  const int* __restrict__ csr_src,
                                                  const float* __restrict__ bias,
                                                  float* __restrict__ Out) {
    __shared__ float sP[8][32][4];   // [waveslot][edge][head], one ds_write_b128/lane
    __shared__ int   sS[8][32];
    const int wave = threadIdx.x >> 6;
    const int lane = threadIdx.x & 63;
    const int sub  = lane >> 5;
    const int sl   = lane & 31;
    const int ws   = wave * 2 + sub;
    const int n = blockIdx.x * 8 + ws;            // grid = NN/8 exactly
    const int start = row_ptr[n], end = row_ptr[n + 1];
    const int h0 = sl >> 3;                       // head of this lane's 4 channels
    const float4 adv = *(const float4*)&AD[n * NH];
    float spm = 0.f;                              // running sum of pm for head h0
    float acc0 = 0.f, acc1 = 0.f, acc2 = 0.f, acc3 = 0.f;

    for (int base = start; base < end; base += 32) {
        int cn = end - base; if (cn > 32) cn = 32;
        int my_src = 0;
        float al[NH] = {0.f, 0.f, 0.f, 0.f};
        if (sl < cn) {
            my_src = csr_src[base + sl];
            float4 asv = *(const float4*)&AS[my_src * NH];
            al[0] = asv.x + adv.x; al[1] = asv.y + adv.y;
            al[2] = asv.z + adv.z; al[3] = asv.w + adv.w;
        }
        sS[ws][sl] = my_src;
        float4 pv;
        {
            float a0 = (al[0] > 0.f) ? al[0] : NEG_SLOPE * al[0];
            float a1 = (al[1] > 0.f) ? al[1] : NEG_SLOPE * al[1];
            float a2 = (al[2] > 0.f) ? al[2] : NEG_SLOPE * al[2];
            float a3 = (al[3] > 0.f) ? al[3] : NEG_SLOPE * al[3];
            pv.x = __expf(a0); pv.y = __expf(a1);
            pv.z = __expf(a2); pv.w = __expf(a3);
        }
        *(float4*)&sP[ws][sl][0] = pv;            // entries e>=cn never read
        #pragma unroll 4
        for (int e = 0; e < cn; ++e) {
            float pm = sP[ws][e][h0];
            int se = sS[ws][e];
            union { uint2 u; half2v h[2]; } hv;
            hv.u = *(const uint2*)&H[(size_t)se * FD + sl * 4];
            acc0 += (float)hv.h[0][0] * pm;       // v_fma_mix_f32
            acc1 += (float)hv.h[0][1] * pm;
            acc2 += (float)hv.h[1][0] * pm;
            acc3 += (float)hv.h[1][1] * pm;
            spm  += pm;
        }
    }
    float inv = 1.f / (spm + 1e-16f);
    const float4 bv = *(const float4*)&bias[sl * 4];
    float4 ov;
    ov.x = fmaxf(acc0 * inv + bv.x, 0.f);
    ov.y = fmaxf(acc1 * inv + bv.y, 0.f);
    ov.z = fmaxf(acc2 * inv + bv.z, 0.f);
    ov.w = fmaxf(acc3 * inv + bv.w, 0.f);
    *(float4*)&Out[(size_t)n * FD + sl * 4] = ov;
}

// ---------------- launch (7 dispatches) ----------------

extern "C" void kernel_launch(void* const* d_in, const int* in_sizes, int n_in,
                              void* d_out, int out_size, void* d_ws, size_t ws_size,
                              hipStream_t stream) {
    const float* x     = (const float*)d_in[0];
    const int*   ei    = (const int*)d_in[1];
    const float* W1    = (const float*)d_in[2];
    const float* asrc1 = (const float*)d_in[3];
    const float* adst1 = (const float*)d_in[4];
    const float* b1    = (const float*)d_in[5];
    const float* W2    = (const float*)d_in[6];
    const float* asrc2 = (const float*)d_in[7];
    const float* adst2 = (const float*)d_in[8];
    const float* b2    = (const float*)d_in[9];
    float* out = (float*)d_out;

    char* p = (char*)d_ws;
    auto alloc = [&](size_t bytes) {
        char* q = p;
        p += (bytes + 255) & ~(size_t)255;
        return q;
    };
    int*      row_ptr = (int*)alloc((NN + 1) * sizeof(int));
    int*      gcnt    = (int*)alloc(NBKT * sizeof(int));
    uint32_t* gbkt    = (uint32_t*)alloc((size_t)NBKT * CAPG * sizeof(uint32_t));
    int*      csr     = (int*)alloc((size_t)ETOT * sizeof(int));
    float*    AS      = (float*)alloc((size_t)NN * NH * sizeof(float));
    float*    AD      = (float*)alloc((size_t)NN * NH * sizeof(float));
    __half*   Hh      = (__half*)alloc((size_t)NN * FD * sizeof(__half));
    uint4*    Wf1     = (uint4*)alloc(2048 * sizeof(uint4));
    uint4*    Wf2     = (uint4*)alloc(2048 * sizeof(uint4));
    (void)ws_size; (void)in_sizes; (void)n_in; (void)out_size;

    // D1: zero gcnt || W-prep (both layers)
    init_kernel<<<3, 256, 0, stream>>>(gcnt, W1, W2, Wf1, Wf2);
    // D2: bin edges || gemm layer 1
    binGemm_kernel<<<P1_BLOCKS + GEMM_BLOCKS, 256, 0, stream>>>(ei, gcnt, gbkt, x, Wf1, Hh);
    // D3: bucket sort || adot layer 1
    sortAdot_kernel<<<NBKT + ADOT_BLOCKS, 1024, 0, stream>>>(gcnt, gbkt, row_ptr, csr,
                                                             Hh, asrc1, adst1, AS, AD);
    // D4: agg layer 1
    agg_kernel<<<NN / 8, 256, 0, stream>>>(Hh, AS, AD, row_ptr, csr, b1, out);
    // D5-D7: layer 2
    gemm_kernel<<<GEMM_BLOCKS, 256, 0, stream>>>(out, Wf2, Hh);
    adot_kernel<<<(NN * 16 + 255) / 256, 256, 0, stream>>>(Hh, asrc2, adst2, AS, AD);
    agg_kernel<<<NN / 8, 256, 0, stream>>>(Hh, AS, AD, row_ptr, csr, b2, out);
}